// Round 1
// baseline (869.737 us; speedup 1.0000x reference)
//
#include <hip/hip_runtime.h>
#include <hip/hip_bf16.h>

// Sparse MoE: router (RMSNorm+softmax+top2) -> gather rows per expert ->
// gate/up GEMM (bf16 MFMA, fused SiLU*up) -> down GEMM -> weighted atomic scatter.
// T=4096 tokens, D=2048, E=8, F_E=1024, top-2, SCALE=4.

#define TOK 4096
#define DIM 2048
#define NE 8
#define FE 1024
#define SCALE_F 4.0f

#define BM 128
#define BN 128
#define BK 32
#define PAD 8   // LDS row pad (bf16 elems) -> row stride 80B, keeps 16B align

typedef __bf16 bf16x8 __attribute__((ext_vector_type(8)));
typedef __bf16 bf16x4 __attribute__((ext_vector_type(4)));
typedef float f32x4 __attribute__((ext_vector_type(4)));

// ---------------- router: RMSNorm -> logits -> softmax top2 -> counts; x->bf16 ----
__global__ __launch_bounds__(256) void k_router(
    const float* __restrict__ x, const float* __restrict__ rw,
    const float* __restrict__ nw, __bf16* __restrict__ xbf,
    int* __restrict__ topi, float* __restrict__ topw, int* __restrict__ counts) {
  int t = blockIdx.x;
  int tid = threadIdx.x;
  const float* xr = x + (size_t)t * DIM;
  float ssq = 0.f;
  float pe[NE];
#pragma unroll
  for (int e = 0; e < NE; ++e) pe[e] = 0.f;

#pragma unroll
  for (int i = 0; i < 2; ++i) {
    int c4 = tid + i * 256;               // float4 index within row (512 total)
    float4 v = ((const float4*)xr)[c4];
    int c = c4 * 4;
    bf16x4 b;
    b[0] = (__bf16)v.x; b[1] = (__bf16)v.y; b[2] = (__bf16)v.z; b[3] = (__bf16)v.w;
    *(bf16x4*)(xbf + (size_t)t * DIM + c) = b;   // experts use RAW hidden
    float xs[4] = {v.x, v.y, v.z, v.w};
#pragma unroll
    for (int j = 0; j < 4; ++j) {
      float xc = xs[j];
      ssq += xc * xc;
      float m = nw[c + j] * xc;           // rsqrt factored out (applied post-reduce)
#pragma unroll
      for (int e = 0; e < NE; ++e) pe[e] += m * rw[e * DIM + c + j];
    }
  }
  // wave reduce (64 lanes), then cross-wave via LDS
#pragma unroll
  for (int off = 32; off > 0; off >>= 1) {
    ssq += __shfl_down(ssq, off);
#pragma unroll
    for (int e = 0; e < NE; ++e) pe[e] += __shfl_down(pe[e], off);
  }
  __shared__ float red[4][NE + 1];
  int wid = tid >> 6, lane = tid & 63;
  if (lane == 0) {
    red[wid][0] = ssq;
#pragma unroll
    for (int e = 0; e < NE; ++e) red[wid][1 + e] = pe[e];
  }
  __syncthreads();
  if (tid == 0) {
    float s = red[0][0] + red[1][0] + red[2][0] + red[3][0];
    float rs = rsqrtf(s / (float)DIM + 1e-6f);
    float l[NE];
#pragma unroll
    for (int e = 0; e < NE; ++e)
      l[e] = (red[0][1 + e] + red[1][1 + e] + red[2][1 + e] + red[3][1 + e]) * rs;
    int i1 = 0;
#pragma unroll
    for (int e = 1; e < NE; ++e) if (l[e] > l[i1]) i1 = e;
    int i2 = -1;
#pragma unroll
    for (int e = 0; e < NE; ++e) if (e != i1 && (i2 < 0 || l[e] > l[i2])) i2 = e;
    float e2 = __expf(l[i2] - l[i1]);
    float inv = 1.f / (1.f + e2);
    topi[2 * t] = i1; topi[2 * t + 1] = i2;
    topw[2 * t] = inv; topw[2 * t + 1] = e2 * inv;
    atomicAdd(&counts[i1], 1);
    atomicAdd(&counts[i2], 1);
  }
}

// ---------------- prefix sum over 8 experts ----------------
__global__ void k_prefix(const int* __restrict__ counts, int* __restrict__ offsets,
                         int* __restrict__ cursor) {
  if (threadIdx.x == 0 && blockIdx.x == 0) {
    int acc = 0;
    for (int e = 0; e < NE; ++e) {
      offsets[e] = acc;
      cursor[e] = acc;
      acc += counts[e];
    }
    offsets[NE] = acc;   // == 2*TOK
  }
}

// ---------------- place tokens into gathered row list ----------------
__global__ __launch_bounds__(256) void k_place(
    const int* __restrict__ topi, const float* __restrict__ topw,
    int* __restrict__ cursor, int* __restrict__ row_token, float* __restrict__ row_wt) {
  int t = blockIdx.x * 256 + threadIdx.x;
  if (t >= TOK) return;
#pragma unroll
  for (int s = 0; s < 2; ++s) {
    int e = topi[2 * t + s];
    int pos = atomicAdd(&cursor[e], 1);
    row_token[pos] = t;
    row_wt[pos] = topw[2 * t + s] * SCALE_F;
  }
}

// ---------------- gate/up fused GEMM + SiLU epilogue ----------------
// grid: x = FE/BN (8), y = max row tiles (32), z = expert (8)
__global__ __launch_bounds__(256) void k_gateup(
    const __bf16* __restrict__ xbf, const float* __restrict__ gw,
    const float* __restrict__ uw, const int* __restrict__ row_token,
    const int* __restrict__ offsets, __bf16* __restrict__ abuf) {
  int e = blockIdx.z;
  int row_start = offsets[e], row_end = offsets[e + 1];
  int tile_row = row_start + blockIdx.y * BM;
  if (tile_row >= row_end) return;
  int n0 = blockIdx.x * BN;

  __shared__ __align__(16) __bf16 As[BM][BK + PAD];
  __shared__ __align__(16) __bf16 Bgs[BN][BK + PAD];
  __shared__ __align__(16) __bf16 Bus[BN][BK + PAD];
  __shared__ int toks[BM];

  int tid = threadIdx.x;
  if (tid < BM) {
    int r = tile_row + tid;
    toks[tid] = (r < row_end) ? row_token[r] : row_token[row_start];
  }
  __syncthreads();

  f32x4 accg[4][4]; f32x4 accu[4][4];
#pragma unroll
  for (int i = 0; i < 4; ++i)
#pragma unroll
    for (int j = 0; j < 4; ++j) { accg[i][j] = (f32x4)0.f; accu[i][j] = (f32x4)0.f; }

  int wid = tid >> 6, lane = tid & 63;
  int wm = (wid >> 1) * 64, wn = (wid & 1) * 64;
  int lr = lane & 15, lk = (lane >> 4) * 8;

  const float* gbase = gw + (size_t)e * DIM * FE + n0;
  const float* ubase = uw + (size_t)e * DIM * FE + n0;
  int n4 = (tid & 31) * 4;   // B staging: column group
  int kb = tid >> 5;         // B staging: k row (0..7)

  for (int k0 = 0; k0 < DIM; k0 += BK) {
    // stage A (128x32 bf16), gathered rows
#pragma unroll
    for (int p = 0; p < 2; ++p) {
      int g = tid + p * 256;
      int r = g >> 2, kk = (g & 3) * 8;
      bf16x8 v = *(const bf16x8*)(xbf + (size_t)toks[r] * DIM + k0 + kk);
      *(bf16x8*)&As[r][kk] = v;
    }
    // stage B gate+up: global [k][n] f32 -> LDS [n][k] bf16
#pragma unroll
    for (int p = 0; p < 4; ++p) {
      int k = kb + p * 8;
      const float4 vg = *(const float4*)(gbase + (size_t)(k0 + k) * FE + n4);
      const float4 vu = *(const float4*)(ubase + (size_t)(k0 + k) * FE + n4);
      Bgs[n4 + 0][k] = (__bf16)vg.x; Bgs[n4 + 1][k] = (__bf16)vg.y;
      Bgs[n4 + 2][k] = (__bf16)vg.z; Bgs[n4 + 3][k] = (__bf16)vg.w;
      Bus[n4 + 0][k] = (__bf16)vu.x; Bus[n4 + 1][k] = (__bf16)vu.y;
      Bus[n4 + 2][k] = (__bf16)vu.z; Bus[n4 + 3][k] = (__bf16)vu.w;
    }
    __syncthreads();

    bf16x8 af[4];
#pragma unroll
    for (int mi = 0; mi < 4; ++mi)
      af[mi] = *(const bf16x8*)&As[wm + mi * 16 + lr][lk];
#pragma unroll
    for (int ni = 0; ni < 4; ++ni) {
      bf16x8 bg = *(const bf16x8*)&Bgs[wn + ni * 16 + lr][lk];
      bf16x8 bu = *(const bf16x8*)&Bus[wn + ni * 16 + lr][lk];
#pragma unroll
      for (int mi = 0; mi < 4; ++mi) {
        accg[mi][ni] = __builtin_amdgcn_mfma_f32_16x16x32_bf16(af[mi], bg, accg[mi][ni], 0, 0, 0);
        accu[mi][ni] = __builtin_amdgcn_mfma_f32_16x16x32_bf16(af[mi], bu, accu[mi][ni], 0, 0, 0);
      }
    }
    __syncthreads();
  }

  // epilogue: a = silu(g)*u -> abuf (bf16), guarded to this expert's rows
  int rowq = (lane >> 4) * 4;
#pragma unroll
  for (int mi = 0; mi < 4; ++mi) {
#pragma unroll
    for (int ni = 0; ni < 4; ++ni) {
#pragma unroll
      for (int j = 0; j < 4; ++j) {
        int rg = tile_row + wm + mi * 16 + rowq + j;
        if (rg < row_end) {
          float g = accg[mi][ni][j], u = accu[mi][ni][j];
          float sig = 1.f / (1.f + __expf(-g));
          float a = g * sig * u;
          abuf[(size_t)rg * FE + n0 + wn + ni * 16 + lr] = (__bf16)a;
        }
      }
    }
  }
}

// ---------------- down GEMM + weighted atomic scatter ----------------
// grid: x = DIM/BN (16), y = max row tiles (32), z = expert (8)
__global__ __launch_bounds__(256) void k_down(
    const __bf16* __restrict__ abuf, const float* __restrict__ dw,
    const int* __restrict__ row_token, const float* __restrict__ row_wt,
    const int* __restrict__ offsets, float* __restrict__ out) {
  int e = blockIdx.z;
  int row_start = offsets[e], row_end = offsets[e + 1];
  int tile_row = row_start + blockIdx.y * BM;
  if (tile_row >= row_end) return;
  int n0 = blockIdx.x * BN;

  __shared__ __align__(16) __bf16 As[BM][BK + PAD];
  __shared__ __align__(16) __bf16 Bs[BN][BK + PAD];

  int tid = threadIdx.x;
  f32x4 acc[4][4];
#pragma unroll
  for (int i = 0; i < 4; ++i)
#pragma unroll
    for (int j = 0; j < 4; ++j) acc[i][j] = (f32x4)0.f;

  int wid = tid >> 6, lane = tid & 63;
  int wm = (wid >> 1) * 64, wn = (wid & 1) * 64;
  int lr = lane & 15, lk = (lane >> 4) * 8;

  const float* dbase = dw + (size_t)e * FE * DIM + n0;
  int n4 = (tid & 31) * 4;
  int kb = tid >> 5;

  for (int k0 = 0; k0 < FE; k0 += BK) {
    // stage A from abuf (rows already gathered/contiguous)
#pragma unroll
    for (int p = 0; p < 2; ++p) {
      int g = tid + p * 256;
      int r = g >> 2, kk = (g & 3) * 8;
      bf16x8 v = *(const bf16x8*)(abuf + (size_t)(tile_row + r) * FE + k0 + kk);
      *(bf16x8*)&As[r][kk] = v;
    }
    // stage B: dw [k=f][n=d] f32 -> LDS [n][k] bf16
#pragma unroll
    for (int p = 0; p < 4; ++p) {
      int k = kb + p * 8;
      const float4 vb = *(const float4*)(dbase + (size_t)(k0 + k) * DIM + n4);
      Bs[n4 + 0][k] = (__bf16)vb.x; Bs[n4 + 1][k] = (__bf16)vb.y;
      Bs[n4 + 2][k] = (__bf16)vb.z; Bs[n4 + 3][k] = (__bf16)vb.w;
    }
    __syncthreads();

    bf16x8 af[4];
#pragma unroll
    for (int mi = 0; mi < 4; ++mi)
      af[mi] = *(const bf16x8*)&As[wm + mi * 16 + lr][lk];
#pragma unroll
    for (int ni = 0; ni < 4; ++ni) {
      bf16x8 bb = *(const bf16x8*)&Bs[wn + ni * 16 + lr][lk];
#pragma unroll
      for (int mi = 0; mi < 4; ++mi)
        acc[mi][ni] = __builtin_amdgcn_mfma_f32_16x16x32_bf16(af[mi], bb, acc[mi][ni], 0, 0, 0);
    }
    __syncthreads();
  }

  // epilogue: out[token] += acc * (topw * SCALE)
  int rowq = (lane >> 4) * 4;
#pragma unroll
  for (int mi = 0; mi < 4; ++mi) {
#pragma unroll
    for (int j = 0; j < 4; ++j) {
      int rg = tile_row + wm + mi * 16 + rowq + j;
      if (rg < row_end) {
        int tok = row_token[rg];
        float w = row_wt[rg];
#pragma unroll
        for (int ni = 0; ni < 4; ++ni) {
          atomicAdd(&out[(size_t)tok * DIM + n0 + wn + ni * 16 + lr],
                    acc[mi][ni][j] * w);
        }
      }
    }
  }
}

extern "C" void kernel_launch(void* const* d_in, const int* in_sizes, int n_in,
                              void* d_out, int out_size, void* d_ws, size_t ws_size,
                              hipStream_t stream) {
  const float* x  = (const float*)d_in[0];   // hidden_states [2,2048,2048]
  const float* rw = (const float*)d_in[1];   // router_w [8,2048]
  const float* nw = (const float*)d_in[2];   // norm_w [2048]
  const float* gw = (const float*)d_in[3];   // gate_w [8,2048,1024]
  const float* uw = (const float*)d_in[4];   // up_w   [8,2048,1024]
  const float* dwp= (const float*)d_in[5];   // down_w [8,1024,2048]
  float* out = (float*)d_out;

  char* p = (char*)d_ws;
  int* counts    = (int*)p;                       // 32 B
  int* cursor    = (int*)(p + 32);                // 32 B
  int* offsets   = (int*)(p + 64);                // 36 B
  int* topi      = (int*)(p + 256);               // 32 KB
  float* topw    = (float*)(p + 256 + 32768);     // 32 KB
  int* row_token = (int*)(p + 256 + 65536);       // 32 KB
  float* row_wt  = (float*)(p + 256 + 98304);     // 32 KB
  __bf16* xbf    = (__bf16*)(p + 256 + 131072);   // 16.78 MB
  __bf16* abuf   = xbf + (size_t)TOK * DIM;       // (2T+128)*FE bf16 = 17.04 MB

  hipMemsetAsync(p, 0, 64, stream);                               // counts+cursor
  hipMemsetAsync(d_out, 0, (size_t)TOK * DIM * sizeof(float), stream);

  k_router<<<TOK, 256, 0, stream>>>(x, rw, nw, xbf, topi, topw, counts);
  k_prefix<<<1, 64, 0, stream>>>(counts, offsets, cursor);
  k_place<<<(TOK + 255) / 256, 256, 0, stream>>>(topi, topw, cursor, row_token, row_wt);
  k_gateup<<<dim3(FE / BN, 32, NE), 256, 0, stream>>>(xbf, gw, uw, row_token, offsets, abuf);
  k_down<<<dim3(DIM / BN, 32, NE), 256, 0, stream>>>(abuf, dwp, row_token, row_wt, offsets, out);
}

// Round 2
// 476.067 us; speedup vs baseline: 1.8269x; 1.8269x over previous
//
#include <hip/hip_runtime.h>
#include <hip/hip_bf16.h>

// Sparse MoE v2: one-shot weight f32->bf16 transpose-convert pass, then
// router -> gather -> gate/up GEMM (bf16 MFMA, fused SiLU*up) -> down GEMM
// -> weighted atomic scatter. Fallback to in-kernel transpose if ws too small.
// T=4096 tokens, D=2048, E=8, F_E=1024, top-2, SCALE=4.

#define TOK 4096
#define DIM 2048
#define NE 8
#define FE 1024
#define SCALE_F 4.0f

#define BN 128
#define BK 32
#define PAD 8   // LDS row pad (bf16 elems) -> row stride 80B

typedef __bf16 bf16x8 __attribute__((ext_vector_type(8)));
typedef __bf16 bf16x4 __attribute__((ext_vector_type(4)));
typedef float f32x4 __attribute__((ext_vector_type(4)));

// ---------------- router: RMSNorm -> logits -> softmax top2 -> counts; x->bf16 ----
__global__ __launch_bounds__(256) void k_router(
    const float* __restrict__ x, const float* __restrict__ rw,
    const float* __restrict__ nw, __bf16* __restrict__ xbf,
    int* __restrict__ topi, float* __restrict__ topw, int* __restrict__ counts) {
  int t = blockIdx.x;
  int tid = threadIdx.x;
  const float* xr = x + (size_t)t * DIM;
  float ssq = 0.f;
  float pe[NE];
#pragma unroll
  for (int e = 0; e < NE; ++e) pe[e] = 0.f;

#pragma unroll
  for (int i = 0; i < 2; ++i) {
    int c4 = tid + i * 256;               // float4 index within row (512 total)
    float4 v = ((const float4*)xr)[c4];
    int c = c4 * 4;
    bf16x4 b;
    b[0] = (__bf16)v.x; b[1] = (__bf16)v.y; b[2] = (__bf16)v.z; b[3] = (__bf16)v.w;
    *(bf16x4*)(xbf + (size_t)t * DIM + c) = b;   // experts use RAW hidden
    float xs[4] = {v.x, v.y, v.z, v.w};
#pragma unroll
    for (int j = 0; j < 4; ++j) {
      float xc = xs[j];
      ssq += xc * xc;
      float m = nw[c + j] * xc;           // rsqrt factored out (applied post-reduce)
#pragma unroll
      for (int e = 0; e < NE; ++e) pe[e] += m * rw[e * DIM + c + j];
    }
  }
#pragma unroll
  for (int off = 32; off > 0; off >>= 1) {
    ssq += __shfl_down(ssq, off);
#pragma unroll
    for (int e = 0; e < NE; ++e) pe[e] += __shfl_down(pe[e], off);
  }
  __shared__ float red[4][NE + 1];
  int wid = tid >> 6, lane = tid & 63;
  if (lane == 0) {
    red[wid][0] = ssq;
#pragma unroll
    for (int e = 0; e < NE; ++e) red[wid][1 + e] = pe[e];
  }
  __syncthreads();
  if (tid == 0) {
    float s = red[0][0] + red[1][0] + red[2][0] + red[3][0];
    float rs = rsqrtf(s / (float)DIM + 1e-6f);
    float l[NE];
#pragma unroll
    for (int e = 0; e < NE; ++e)
      l[e] = (red[0][1 + e] + red[1][1 + e] + red[2][1 + e] + red[3][1 + e]) * rs;
    int i1 = 0;
#pragma unroll
    for (int e = 1; e < NE; ++e) if (l[e] > l[i1]) i1 = e;
    int i2 = -1;
#pragma unroll
    for (int e = 0; e < NE; ++e) if (e != i1 && (i2 < 0 || l[e] > l[i2])) i2 = e;
    float e2 = __expf(l[i2] - l[i1]);
    float inv = 1.f / (1.f + e2);
    topi[2 * t] = i1; topi[2 * t + 1] = i2;
    topw[2 * t] = inv; topw[2 * t + 1] = e2 * inv;
    atomicAdd(&counts[i1], 1);
    atomicAdd(&counts[i2], 1);
  }
}

// ---------------- prefix sum over 8 experts ----------------
__global__ void k_prefix(const int* __restrict__ counts, int* __restrict__ offsets,
                         int* __restrict__ cursor) {
  if (threadIdx.x == 0 && blockIdx.x == 0) {
    int acc = 0;
    for (int e = 0; e < NE; ++e) {
      offsets[e] = acc;
      cursor[e] = acc;
      acc += counts[e];
    }
    offsets[NE] = acc;   // == 2*TOK
  }
}

// ---------------- place tokens into gathered row list ----------------
__global__ __launch_bounds__(256) void k_place(
    const int* __restrict__ topi, const float* __restrict__ topw,
    int* __restrict__ cursor, int* __restrict__ row_token, float* __restrict__ row_wt) {
  int t = blockIdx.x * 256 + threadIdx.x;
  if (t >= TOK) return;
#pragma unroll
  for (int s = 0; s < 2; ++s) {
    int e = topi[2 * t + s];
    int pos = atomicAdd(&cursor[e], 1);
    row_token[pos] = t;
    row_wt[pos] = topw[2 * t + s] * SCALE_F;
  }
}

// ---------------- transpose + f32->bf16 convert: in [E][R][C] -> out [E][C][R] ----
__global__ __launch_bounds__(256) void k_tcvt(
    const float* __restrict__ in, __bf16* __restrict__ out, int R, int C) {
  __shared__ float tile[32][33];
  const float* src = in + (size_t)blockIdx.z * R * C;
  __bf16* dst = out + (size_t)blockIdx.z * R * C;
  int c0 = blockIdx.x * 32, r0 = blockIdx.y * 32;
  int tid = threadIdx.x;
  // load 32x32 f32, vectorized: 8 float4 per row
  int ty = tid >> 3, tx4 = (tid & 7) * 4;
  float4 v = *(const float4*)(src + (size_t)(r0 + ty) * C + c0 + tx4);
  tile[ty][tx4 + 0] = v.x; tile[ty][tx4 + 1] = v.y;
  tile[ty][tx4 + 2] = v.z; tile[ty][tx4 + 3] = v.w;
  __syncthreads();
  // store transposed as bf16x4
  int oc = tid >> 3, or4 = (tid & 7) * 4;
  bf16x4 w;
#pragma unroll
  for (int j = 0; j < 4; ++j) w[j] = (__bf16)tile[or4 + j][oc];
  *(bf16x4*)(dst + (size_t)(c0 + oc) * R + r0 + or4) = w;
}

// ================= FAST PATH (pre-converted bf16 transposed weights) ==========

// gate/up fused GEMM + SiLU epilogue. Tile 64x128, 4 waves (2x2), per-wave 32x64.
// grid: x = FE/BN (8), y = 64 row tiles, z = expert (8)
__global__ __launch_bounds__(256) void k_gateup2(
    const __bf16* __restrict__ xbf, const __bf16* __restrict__ gwt,
    const __bf16* __restrict__ uwt, const int* __restrict__ row_token,
    const int* __restrict__ offsets, __bf16* __restrict__ abuf) {
  int e = blockIdx.z;
  int row_start = offsets[e], row_end = offsets[e + 1];
  int tile_row = row_start + blockIdx.y * 64;
  if (tile_row >= row_end) return;
  int n0 = blockIdx.x * BN;

  __shared__ __align__(16) __bf16 As[64][BK + PAD];
  __shared__ __align__(16) __bf16 Bgs[BN][BK + PAD];
  __shared__ __align__(16) __bf16 Bus[BN][BK + PAD];
  __shared__ int toks[64];

  int tid = threadIdx.x;
  if (tid < 64) {
    int r = tile_row + tid;
    toks[tid] = (r < row_end) ? row_token[r] : row_token[row_start];
  }
  __syncthreads();

  f32x4 accg[2][4]; f32x4 accu[2][4];
#pragma unroll
  for (int i = 0; i < 2; ++i)
#pragma unroll
    for (int j = 0; j < 4; ++j) { accg[i][j] = (f32x4)0.f; accu[i][j] = (f32x4)0.f; }

  int wid = tid >> 6, lane = tid & 63;
  int wm = (wid >> 1) * 32, wn = (wid & 1) * 64;
  int lr = lane & 15, lk = (lane >> 4) * 8;

  const __bf16* gb = gwt + (size_t)e * FE * DIM + (size_t)n0 * DIM;  // [n][k]
  const __bf16* ub = uwt + (size_t)e * FE * DIM + (size_t)n0 * DIM;
  int sr = tid >> 2, skk = (tid & 3) * 8;

  for (int k0 = 0; k0 < DIM; k0 += BK) {
    // A: 64x32 gathered rows (one pass)
    *(bf16x8*)&As[sr][skk] = *(const bf16x8*)(xbf + (size_t)toks[sr] * DIM + k0 + skk);
    // Bg, Bu: 128x32, two passes each, straight bf16x8 copies
#pragma unroll
    for (int p = 0; p < 2; ++p) {
      int g = tid + p * 256;
      int r = g >> 2, kk = (g & 3) * 8;
      *(bf16x8*)&Bgs[r][kk] = *(const bf16x8*)(gb + (size_t)r * DIM + k0 + kk);
      *(bf16x8*)&Bus[r][kk] = *(const bf16x8*)(ub + (size_t)r * DIM + k0 + kk);
    }
    __syncthreads();

    bf16x8 af[2];
#pragma unroll
    for (int mi = 0; mi < 2; ++mi)
      af[mi] = *(const bf16x8*)&As[wm + mi * 16 + lr][lk];
#pragma unroll
    for (int ni = 0; ni < 4; ++ni) {
      bf16x8 bg = *(const bf16x8*)&Bgs[wn + ni * 16 + lr][lk];
      bf16x8 bu = *(const bf16x8*)&Bus[wn + ni * 16 + lr][lk];
#pragma unroll
      for (int mi = 0; mi < 2; ++mi) {
        accg[mi][ni] = __builtin_amdgcn_mfma_f32_16x16x32_bf16(af[mi], bg, accg[mi][ni], 0, 0, 0);
        accu[mi][ni] = __builtin_amdgcn_mfma_f32_16x16x32_bf16(af[mi], bu, accu[mi][ni], 0, 0, 0);
      }
    }
    __syncthreads();
  }

  int rowq = (lane >> 4) * 4;
#pragma unroll
  for (int mi = 0; mi < 2; ++mi) {
#pragma unroll
    for (int ni = 0; ni < 4; ++ni) {
#pragma unroll
      for (int j = 0; j < 4; ++j) {
        int rg = tile_row + wm + mi * 16 + rowq + j;
        if (rg < row_end) {
          float g = accg[mi][ni][j], u = accu[mi][ni][j];
          float sig = 1.f / (1.f + __expf(-g));
          abuf[(size_t)rg * FE + n0 + wn + ni * 16 + lr] = (__bf16)(g * sig * u);
        }
      }
    }
  }
}

// down GEMM + weighted atomic scatter. Tile 128x128.
// grid: x = DIM/BN (16), y = 32, z = expert (8)
__global__ __launch_bounds__(256) void k_down2(
    const __bf16* __restrict__ abuf, const __bf16* __restrict__ dwt,
    const int* __restrict__ row_token, const float* __restrict__ row_wt,
    const int* __restrict__ offsets, float* __restrict__ out) {
  int e = blockIdx.z;
  int row_start = offsets[e], row_end = offsets[e + 1];
  int tile_row = row_start + blockIdx.y * 128;
  if (tile_row >= row_end) return;
  int n0 = blockIdx.x * BN;

  __shared__ __align__(16) __bf16 As[128][BK + PAD];
  __shared__ __align__(16) __bf16 Bs[BN][BK + PAD];

  int tid = threadIdx.x;
  f32x4 acc[4][4];
#pragma unroll
  for (int i = 0; i < 4; ++i)
#pragma unroll
    for (int j = 0; j < 4; ++j) acc[i][j] = (f32x4)0.f;

  int wid = tid >> 6, lane = tid & 63;
  int wm = (wid >> 1) * 64, wn = (wid & 1) * 64;
  int lr = lane & 15, lk = (lane >> 4) * 8;

  const __bf16* db = dwt + (size_t)e * DIM * FE + (size_t)n0 * FE;  // [n][k]

  for (int k0 = 0; k0 < FE; k0 += BK) {
#pragma unroll
    for (int p = 0; p < 2; ++p) {
      int g = tid + p * 256;
      int r = g >> 2, kk = (g & 3) * 8;
      *(bf16x8*)&As[r][kk] = *(const bf16x8*)(abuf + (size_t)(tile_row + r) * FE + k0 + kk);
      *(bf16x8*)&Bs[r][kk] = *(const bf16x8*)(db + (size_t)r * FE + k0 + kk);
    }
    __syncthreads();

    bf16x8 af[4];
#pragma unroll
    for (int mi = 0; mi < 4; ++mi)
      af[mi] = *(const bf16x8*)&As[wm + mi * 16 + lr][lk];
#pragma unroll
    for (int ni = 0; ni < 4; ++ni) {
      bf16x8 bb = *(const bf16x8*)&Bs[wn + ni * 16 + lr][lk];
#pragma unroll
      for (int mi = 0; mi < 4; ++mi)
        acc[mi][ni] = __builtin_amdgcn_mfma_f32_16x16x32_bf16(af[mi], bb, acc[mi][ni], 0, 0, 0);
    }
    __syncthreads();
  }

  int rowq = (lane >> 4) * 4;
#pragma unroll
  for (int mi = 0; mi < 4; ++mi) {
#pragma unroll
    for (int j = 0; j < 4; ++j) {
      int rg = tile_row + wm + mi * 16 + rowq + j;
      if (rg < row_end) {
        int tok = row_token[rg];
        float w = row_wt[rg];
#pragma unroll
        for (int ni = 0; ni < 4; ++ni) {
          atomicAdd(&out[(size_t)tok * DIM + n0 + wn + ni * 16 + lr],
                    acc[mi][ni][j] * w);
        }
      }
    }
  }
}

// ================= FALLBACK PATH (round-1 kernels, in-kernel transpose) =======

__global__ __launch_bounds__(256) void k_gateup_fb(
    const __bf16* __restrict__ xbf, const float* __restrict__ gw,
    const float* __restrict__ uw, const int* __restrict__ row_token,
    const int* __restrict__ offsets, __bf16* __restrict__ abuf) {
  int e = blockIdx.z;
  int row_start = offsets[e], row_end = offsets[e + 1];
  int tile_row = row_start + blockIdx.y * 128;
  if (tile_row >= row_end) return;
  int n0 = blockIdx.x * BN;

  __shared__ __align__(16) __bf16 As[128][BK + PAD];
  __shared__ __align__(16) __bf16 Bgs[BN][BK + PAD];
  __shared__ __align__(16) __bf16 Bus[BN][BK + PAD];
  __shared__ int toks[128];

  int tid = threadIdx.x;
  if (tid < 128) {
    int r = tile_row + tid;
    toks[tid] = (r < row_end) ? row_token[r] : row_token[row_start];
  }
  __syncthreads();

  f32x4 accg[4][4]; f32x4 accu[4][4];
#pragma unroll
  for (int i = 0; i < 4; ++i)
#pragma unroll
    for (int j = 0; j < 4; ++j) { accg[i][j] = (f32x4)0.f; accu[i][j] = (f32x4)0.f; }

  int wid = tid >> 6, lane = tid & 63;
  int wm = (wid >> 1) * 64, wn = (wid & 1) * 64;
  int lr = lane & 15, lk = (lane >> 4) * 8;

  const float* gbase = gw + (size_t)e * DIM * FE + n0;
  const float* ubase = uw + (size_t)e * DIM * FE + n0;
  int n4 = (tid & 31) * 4;
  int kb = tid >> 5;

  for (int k0 = 0; k0 < DIM; k0 += BK) {
#pragma unroll
    for (int p = 0; p < 2; ++p) {
      int g = tid + p * 256;
      int r = g >> 2, kk = (g & 3) * 8;
      *(bf16x8*)&As[r][kk] = *(const bf16x8*)(xbf + (size_t)toks[r] * DIM + k0 + kk);
    }
#pragma unroll
    for (int p = 0; p < 4; ++p) {
      int k = kb + p * 8;
      const float4 vg = *(const float4*)(gbase + (size_t)(k0 + k) * FE + n4);
      const float4 vu = *(const float4*)(ubase + (size_t)(k0 + k) * FE + n4);
      Bgs[n4 + 0][k] = (__bf16)vg.x; Bgs[n4 + 1][k] = (__bf16)vg.y;
      Bgs[n4 + 2][k] = (__bf16)vg.z; Bgs[n4 + 3][k] = (__bf16)vg.w;
      Bus[n4 + 0][k] = (__bf16)vu.x; Bus[n4 + 1][k] = (__bf16)vu.y;
      Bus[n4 + 2][k] = (__bf16)vu.z; Bus[n4 + 3][k] = (__bf16)vu.w;
    }
    __syncthreads();

    bf16x8 af[4];
#pragma unroll
    for (int mi = 0; mi < 4; ++mi)
      af[mi] = *(const bf16x8*)&As[wm + mi * 16 + lr][lk];
#pragma unroll
    for (int ni = 0; ni < 4; ++ni) {
      bf16x8 bg = *(const bf16x8*)&Bgs[wn + ni * 16 + lr][lk];
      bf16x8 bu = *(const bf16x8*)&Bus[wn + ni * 16 + lr][lk];
#pragma unroll
      for (int mi = 0; mi < 4; ++mi) {
        accg[mi][ni] = __builtin_amdgcn_mfma_f32_16x16x32_bf16(af[mi], bg, accg[mi][ni], 0, 0, 0);
        accu[mi][ni] = __builtin_amdgcn_mfma_f32_16x16x32_bf16(af[mi], bu, accu[mi][ni], 0, 0, 0);
      }
    }
    __syncthreads();
  }

  int rowq = (lane >> 4) * 4;
#pragma unroll
  for (int mi = 0; mi < 4; ++mi) {
#pragma unroll
    for (int ni = 0; ni < 4; ++ni) {
#pragma unroll
      for (int j = 0; j < 4; ++j) {
        int rg = tile_row + wm + mi * 16 + rowq + j;
        if (rg < row_end) {
          float g = accg[mi][ni][j], u = accu[mi][ni][j];
          float sig = 1.f / (1.f + __expf(-g));
          abuf[(size_t)rg * FE + n0 + wn + ni * 16 + lr] = (__bf16)(g * sig * u);
        }
      }
    }
  }
}

__global__ __launch_bounds__(256) void k_down_fb(
    const __bf16* __restrict__ abuf, const float* __restrict__ dw,
    const int* __restrict__ row_token, const float* __restrict__ row_wt,
    const int* __restrict__ offsets, float* __restrict__ out) {
  int e = blockIdx.z;
  int row_start = offsets[e], row_end = offsets[e + 1];
  int tile_row = row_start + blockIdx.y * 128;
  if (tile_row >= row_end) return;
  int n0 = blockIdx.x * BN;

  __shared__ __align__(16) __bf16 As[128][BK + PAD];
  __shared__ __align__(16) __bf16 Bs[BN][BK + PAD];

  int tid = threadIdx.x;
  f32x4 acc[4][4];
#pragma unroll
  for (int i = 0; i < 4; ++i)
#pragma unroll
    for (int j = 0; j < 4; ++j) acc[i][j] = (f32x4)0.f;

  int wid = tid >> 6, lane = tid & 63;
  int wm = (wid >> 1) * 64, wn = (wid & 1) * 64;
  int lr = lane & 15, lk = (lane >> 4) * 8;

  const float* dbase = dw + (size_t)e * FE * DIM + n0;
  int n4 = (tid & 31) * 4;
  int kb = tid >> 5;

  for (int k0 = 0; k0 < FE; k0 += BK) {
#pragma unroll
    for (int p = 0; p < 2; ++p) {
      int g = tid + p * 256;
      int r = g >> 2, kk = (g & 3) * 8;
      *(bf16x8*)&As[r][kk] = *(const bf16x8*)(abuf + (size_t)(tile_row + r) * FE + k0 + kk);
    }
#pragma unroll
    for (int p = 0; p < 4; ++p) {
      int k = kb + p * 8;
      const float4 vb = *(const float4*)(dbase + (size_t)(k0 + k) * DIM + n4);
      Bs[n4 + 0][k] = (__bf16)vb.x; Bs[n4 + 1][k] = (__bf16)vb.y;
      Bs[n4 + 2][k] = (__bf16)vb.z; Bs[n4 + 3][k] = (__bf16)vb.w;
    }
    __syncthreads();

    bf16x8 af[4];
#pragma unroll
    for (int mi = 0; mi < 4; ++mi)
      af[mi] = *(const bf16x8*)&As[wm + mi * 16 + lr][lk];
#pragma unroll
    for (int ni = 0; ni < 4; ++ni) {
      bf16x8 bb = *(const bf16x8*)&Bs[wn + ni * 16 + lr][lk];
#pragma unroll
      for (int mi = 0; mi < 4; ++mi)
        acc[mi][ni] = __builtin_amdgcn_mfma_f32_16x16x32_bf16(af[mi], bb, acc[mi][ni], 0, 0, 0);
    }
    __syncthreads();
  }

  int rowq = (lane >> 4) * 4;
#pragma unroll
  for (int mi = 0; mi < 4; ++mi) {
#pragma unroll
    for (int j = 0; j < 4; ++j) {
      int rg = tile_row + wm + mi * 16 + rowq + j;
      if (rg < row_end) {
        int tok = row_token[rg];
        float w = row_wt[rg];
#pragma unroll
        for (int ni = 0; ni < 4; ++ni) {
          atomicAdd(&out[(size_t)tok * DIM + n0 + wn + ni * 16 + lr],
                    acc[mi][ni][j] * w);
        }
      }
    }
  }
}

extern "C" void kernel_launch(void* const* d_in, const int* in_sizes, int n_in,
                              void* d_out, int out_size, void* d_ws, size_t ws_size,
                              hipStream_t stream) {
  const float* x  = (const float*)d_in[0];   // hidden_states [2,2048,2048]
  const float* rw = (const float*)d_in[1];   // router_w [8,2048]
  const float* nw = (const float*)d_in[2];   // norm_w [2048]
  const float* gw = (const float*)d_in[3];   // gate_w [8,2048,1024]
  const float* uw = (const float*)d_in[4];   // up_w   [8,2048,1024]
  const float* dwp= (const float*)d_in[5];   // down_w [8,1024,2048]
  float* out = (float*)d_out;

  char* p = (char*)d_ws;
  int* counts    = (int*)p;                       // 32 B
  int* cursor    = (int*)(p + 32);                // 32 B
  int* offsets   = (int*)(p + 64);                // 36 B
  int* topi      = (int*)(p + 256);               // 32 KB
  float* topw    = (float*)(p + 256 + 32768);     // 32 KB
  int* row_token = (int*)(p + 256 + 65536);       // 32 KB
  float* row_wt  = (float*)(p + 256 + 98304);     // 32 KB
  __bf16* xbf    = (__bf16*)(p + 256 + 131072);   // 16.78 MB
  __bf16* abuf   = xbf + (size_t)TOK * DIM;       // (2T+128)*FE bf16
  __bf16* gwt    = abuf + ((size_t)2 * TOK + 128) * FE;  // 33.55 MB each
  __bf16* uwt    = gwt + (size_t)NE * DIM * FE;
  __bf16* dwt    = uwt + (size_t)NE * DIM * FE;

  size_t need = 256 + 131072 +
                ((size_t)TOK * DIM + ((size_t)2 * TOK + 128) * FE) * 2 +
                3 * (size_t)NE * DIM * FE * 2;
  bool fast = ws_size >= need;

  hipMemsetAsync(p, 0, 64, stream);
  hipMemsetAsync(d_out, 0, (size_t)TOK * DIM * sizeof(float), stream);

  if (fast) {
    // gate/up: [E][D][FE] -> [E][FE][D];  down: [E][FE][D] -> [E][D][FE]
    k_tcvt<<<dim3(FE / 32, DIM / 32, NE), 256, 0, stream>>>(gw, gwt, DIM, FE);
    k_tcvt<<<dim3(FE / 32, DIM / 32, NE), 256, 0, stream>>>(uw, uwt, DIM, FE);
    k_tcvt<<<dim3(DIM / 32, FE / 32, NE), 256, 0, stream>>>(dwp, dwt, FE, DIM);
  }

  k_router<<<TOK, 256, 0, stream>>>(x, rw, nw, xbf, topi, topw, counts);
  k_prefix<<<1, 64, 0, stream>>>(counts, offsets, cursor);
  k_place<<<(TOK + 255) / 256, 256, 0, stream>>>(topi, topw, cursor, row_token, row_wt);

  if (fast) {
    k_gateup2<<<dim3(FE / BN, 64, NE), 256, 0, stream>>>(xbf, gwt, uwt, row_token, offsets, abuf);
    k_down2<<<dim3(DIM / BN, 32, NE), 256, 0, stream>>>(abuf, dwt, row_token, row_wt, offsets, out);
  } else {
    k_gateup_fb<<<dim3(FE / BN, 32, NE), 256, 0, stream>>>(xbf, gw, uw, row_token, offsets, abuf);
    k_down_fb<<<dim3(DIM / BN, 32, NE), 256, 0, stream>>>(abuf, dwp, row_token, row_wt, offsets, out);
  }
}

// Round 3
// 406.897 us; speedup vs baseline: 2.1375x; 1.1700x over previous
//
#include <hip/hip_runtime.h>
#include <hip/hip_bf16.h>

// Sparse MoE v3: m97-style GEMMs (global_load_lds width-16 staging, 128-row
// tiles), improved transpose-convert pass (bf16x8 stores).
// T=4096 tokens, D=2048, E=8, F_E=1024, top-2, SCALE=4.

#define TOK 4096
#define DIM 2048
#define NE 8
#define FE 1024
#define SCALE_F 4.0f
#define BK 32

typedef __bf16 bf16x8 __attribute__((ext_vector_type(8)));
typedef __bf16 bf16x4 __attribute__((ext_vector_type(4)));
typedef float f32x4 __attribute__((ext_vector_type(4)));

__device__ __forceinline__ void gll16(const void* g, void* l) {
  __builtin_amdgcn_global_load_lds(
      (const __attribute__((address_space(1))) unsigned int*)g,
      (__attribute__((address_space(3))) unsigned int*)l, 16, 0, 0);
}

// ---------------- router: RMSNorm -> logits -> softmax top2 -> counts; x->bf16 ----
__global__ __launch_bounds__(256) void k_router(
    const float* __restrict__ x, const float* __restrict__ rw,
    const float* __restrict__ nw, __bf16* __restrict__ xbf,
    int* __restrict__ topi, float* __restrict__ topw, int* __restrict__ counts) {
  int t = blockIdx.x;
  int tid = threadIdx.x;
  const float* xr = x + (size_t)t * DIM;
  float ssq = 0.f;
  float pe[NE];
#pragma unroll
  for (int e = 0; e < NE; ++e) pe[e] = 0.f;

#pragma unroll
  for (int i = 0; i < 2; ++i) {
    int c4 = tid + i * 256;
    float4 v = ((const float4*)xr)[c4];
    int c = c4 * 4;
    bf16x4 b;
    b[0] = (__bf16)v.x; b[1] = (__bf16)v.y; b[2] = (__bf16)v.z; b[3] = (__bf16)v.w;
    *(bf16x4*)(xbf + (size_t)t * DIM + c) = b;
    float xs[4] = {v.x, v.y, v.z, v.w};
#pragma unroll
    for (int j = 0; j < 4; ++j) {
      float xc = xs[j];
      ssq += xc * xc;
      float m = nw[c + j] * xc;
#pragma unroll
      for (int e = 0; e < NE; ++e) pe[e] += m * rw[e * DIM + c + j];
    }
  }
#pragma unroll
  for (int off = 32; off > 0; off >>= 1) {
    ssq += __shfl_down(ssq, off);
#pragma unroll
    for (int e = 0; e < NE; ++e) pe[e] += __shfl_down(pe[e], off);
  }
  __shared__ float red[4][NE + 1];
  int wid = tid >> 6, lane = tid & 63;
  if (lane == 0) {
    red[wid][0] = ssq;
#pragma unroll
    for (int e = 0; e < NE; ++e) red[wid][1 + e] = pe[e];
  }
  __syncthreads();
  if (tid == 0) {
    float s = red[0][0] + red[1][0] + red[2][0] + red[3][0];
    float rs = rsqrtf(s / (float)DIM + 1e-6f);
    float l[NE];
#pragma unroll
    for (int e = 0; e < NE; ++e)
      l[e] = (red[0][1 + e] + red[1][1 + e] + red[2][1 + e] + red[3][1 + e]) * rs;
    int i1 = 0;
#pragma unroll
    for (int e = 1; e < NE; ++e) if (l[e] > l[i1]) i1 = e;
    int i2 = -1;
#pragma unroll
    for (int e = 0; e < NE; ++e) if (e != i1 && (i2 < 0 || l[e] > l[i2])) i2 = e;
    float e2 = __expf(l[i2] - l[i1]);
    float inv = 1.f / (1.f + e2);
    topi[2 * t] = i1; topi[2 * t + 1] = i2;
    topw[2 * t] = inv; topw[2 * t + 1] = e2 * inv;
    atomicAdd(&counts[i1], 1);
    atomicAdd(&counts[i2], 1);
  }
}

__global__ void k_prefix(const int* __restrict__ counts, int* __restrict__ offsets,
                         int* __restrict__ cursor) {
  if (threadIdx.x == 0 && blockIdx.x == 0) {
    int acc = 0;
    for (int e = 0; e < NE; ++e) {
      offsets[e] = acc;
      cursor[e] = acc;
      acc += counts[e];
    }
    offsets[NE] = acc;
  }
}

__global__ __launch_bounds__(256) void k_place(
    const int* __restrict__ topi, const float* __restrict__ topw,
    int* __restrict__ cursor, int* __restrict__ row_token, float* __restrict__ row_wt) {
  int t = blockIdx.x * 256 + threadIdx.x;
  if (t >= TOK) return;
#pragma unroll
  for (int s = 0; s < 2; ++s) {
    int e = topi[2 * t + s];
    int pos = atomicAdd(&cursor[e], 1);
    row_token[pos] = t;
    row_wt[pos] = topw[2 * t + s] * SCALE_F;
  }
}

// ---- transpose + f32->bf16: in [E][R][C] -> out [E][C][R]; 64r x 32c tiles ----
__global__ __launch_bounds__(256) void k_tcvt2(
    const float* __restrict__ in, __bf16* __restrict__ out, int R, int C) {
  __shared__ float tile[32][65];   // [c][r], pad -> ~2-way (free) aliasing
  const float* src = in + (size_t)blockIdx.z * R * C;
  __bf16* dst = out + (size_t)blockIdx.z * R * C;
  int r0 = blockIdx.y * 64, c0 = blockIdx.x * 32;
  int tid = threadIdx.x;
#pragma unroll
  for (int p = 0; p < 2; ++p) {
    int idx = tid + p * 256;
    int r = idx >> 3, c4 = (idx & 7) * 4;
    float4 v = *(const float4*)(src + (size_t)(r0 + r) * C + c0 + c4);
    tile[c4 + 0][r] = v.x; tile[c4 + 1][r] = v.y;
    tile[c4 + 2][r] = v.z; tile[c4 + 3][r] = v.w;
  }
  __syncthreads();
  int c = tid >> 3, rg = (tid & 7) * 8;
  bf16x8 w;
#pragma unroll
  for (int j = 0; j < 8; ++j) w[j] = (__bf16)tile[c][rg + j];
  *(bf16x8*)(dst + (size_t)(c0 + c) * R + r0 + rg) = w;   // coalesced 16B
}

// ================= FAST PATH =================================================

// gate/up fused GEMM + SiLU. Tile 128x64 (m-rows x f-cols), 4 waves 2x2,
// per-wave 64x32. global_load_lds staging. grid: x=FE/64(16), y=32, z=8.
__global__ __launch_bounds__(256) void k_gateup3(
    const __bf16* __restrict__ xbf, const __bf16* __restrict__ gwt,
    const __bf16* __restrict__ uwt, const int* __restrict__ row_token,
    const int* __restrict__ offsets, __bf16* __restrict__ abuf) {
  int e = blockIdx.z;
  int row_start = offsets[e], row_end = offsets[e + 1];
  int tile_row = row_start + blockIdx.y * 128;
  if (tile_row >= row_end) return;
  int n0 = blockIdx.x * 64;

  __shared__ __align__(16) __bf16 As[128][BK];
  __shared__ __align__(16) __bf16 Bgs[64][BK];
  __shared__ __align__(16) __bf16 Bus[64][BK];
  __shared__ int toks[128];

  int tid = threadIdx.x;
  if (tid < 128) {
    int r = tile_row + tid;
    toks[tid] = (r < row_end) ? row_token[r] : row_token[row_start];
  }
  __syncthreads();

  int wid = tid >> 6, lane = tid & 63;
  int lrow = lane >> 2;                  // 0..15 (staging row within 16-row chunk)
  int lke = (lane & 3) * 8;              // staging k elem

  // staging sources (per-lane global addrs; gather via toks). Increment by BK.
  const __bf16* pa0 = xbf + (size_t)toks[wid * 32 + lrow] * DIM + lke;
  const __bf16* pa1 = xbf + (size_t)toks[wid * 32 + 16 + lrow] * DIM + lke;
  const __bf16* pg = gwt + ((size_t)e * FE + n0 + wid * 16 + lrow) * DIM + lke;
  const __bf16* pu = uwt + ((size_t)e * FE + n0 + wid * 16 + lrow) * DIM + lke;
  // wave-uniform LDS dests (HW adds lane*16)
  void* la0 = (void*)&As[wid * 32][0];
  void* la1 = (void*)&As[wid * 32 + 16][0];
  void* lg = (void*)&Bgs[wid * 16][0];
  void* lu = (void*)&Bus[wid * 16][0];

  f32x4 accg[4][2], accu[4][2];
#pragma unroll
  for (int i = 0; i < 4; ++i)
#pragma unroll
    for (int j = 0; j < 2; ++j) { accg[i][j] = (f32x4)0.f; accu[i][j] = (f32x4)0.f; }

  int lr = lane & 15, lk = (lane >> 4) * 8;
  int wm = (wid >> 1) * 64, wn = (wid & 1) * 32;

  for (int k0 = 0; k0 < DIM; k0 += BK) {
    gll16(pa0, la0); gll16(pa1, la1); gll16(pg, lg); gll16(pu, lu);
    pa0 += BK; pa1 += BK; pg += BK; pu += BK;
    __syncthreads();

    bf16x8 af[4];
#pragma unroll
    for (int mi = 0; mi < 4; ++mi)
      af[mi] = *(const bf16x8*)&As[wm + mi * 16 + lr][lk];
#pragma unroll
    for (int ni = 0; ni < 2; ++ni) {
      bf16x8 bg = *(const bf16x8*)&Bgs[wn + ni * 16 + lr][lk];
      bf16x8 bu = *(const bf16x8*)&Bus[wn + ni * 16 + lr][lk];
#pragma unroll
      for (int mi = 0; mi < 4; ++mi) {
        accg[mi][ni] = __builtin_amdgcn_mfma_f32_16x16x32_bf16(af[mi], bg, accg[mi][ni], 0, 0, 0);
        accu[mi][ni] = __builtin_amdgcn_mfma_f32_16x16x32_bf16(af[mi], bu, accu[mi][ni], 0, 0, 0);
      }
    }
    __syncthreads();
  }

  int rowq = (lane >> 4) * 4;
#pragma unroll
  for (int mi = 0; mi < 4; ++mi) {
#pragma unroll
    for (int ni = 0; ni < 2; ++ni) {
#pragma unroll
      for (int j = 0; j < 4; ++j) {
        int rg = tile_row + wm + mi * 16 + rowq + j;
        if (rg < row_end) {
          float g = accg[mi][ni][j], u = accu[mi][ni][j];
          float sig = 1.f / (1.f + __expf(-g));
          abuf[(size_t)rg * FE + n0 + wn + ni * 16 + lr] = (__bf16)(g * sig * u);
        }
      }
    }
  }
}

// down GEMM + weighted atomic scatter. Tile 128x128, m97 structure.
// grid: x=DIM/128(16), y=32, z=8.
__global__ __launch_bounds__(256) void k_down3(
    const __bf16* __restrict__ abuf, const __bf16* __restrict__ dwt,
    const int* __restrict__ row_token, const float* __restrict__ row_wt,
    const int* __restrict__ offsets, float* __restrict__ out) {
  int e = blockIdx.z;
  int row_start = offsets[e], row_end = offsets[e + 1];
  int tile_row = row_start + blockIdx.y * 128;
  if (tile_row >= row_end) return;
  int n0 = blockIdx.x * 128;

  __shared__ __align__(16) __bf16 As[128][BK];
  __shared__ __align__(16) __bf16 Bs[128][BK];

  int tid = threadIdx.x;
  int wid = tid >> 6, lane = tid & 63;
  int lrow = lane >> 2;
  int lke = (lane & 3) * 8;

  const __bf16* pa0 = abuf + (size_t)(tile_row + wid * 32 + lrow) * FE + lke;
  const __bf16* pa1 = pa0 + (size_t)16 * FE;
  const __bf16* pb0 = dwt + ((size_t)e * DIM + n0 + wid * 32 + lrow) * FE + lke;
  const __bf16* pb1 = pb0 + (size_t)16 * FE;
  void* la0 = (void*)&As[wid * 32][0];
  void* la1 = (void*)&As[wid * 32 + 16][0];
  void* lb0 = (void*)&Bs[wid * 32][0];
  void* lb1 = (void*)&Bs[wid * 32 + 16][0];

  f32x4 acc[4][4];
#pragma unroll
  for (int i = 0; i < 4; ++i)
#pragma unroll
    for (int j = 0; j < 4; ++j) acc[i][j] = (f32x4)0.f;

  int lr = lane & 15, lk = (lane >> 4) * 8;
  int wm = (wid >> 1) * 64, wn = (wid & 1) * 64;

  for (int k0 = 0; k0 < FE; k0 += BK) {
    gll16(pa0, la0); gll16(pa1, la1); gll16(pb0, lb0); gll16(pb1, lb1);
    pa0 += BK; pa1 += BK; pb0 += BK; pb1 += BK;
    __syncthreads();

    bf16x8 af[4];
#pragma unroll
    for (int mi = 0; mi < 4; ++mi)
      af[mi] = *(const bf16x8*)&As[wm + mi * 16 + lr][lk];
#pragma unroll
    for (int ni = 0; ni < 4; ++ni) {
      bf16x8 bb = *(const bf16x8*)&Bs[wn + ni * 16 + lr][lk];
#pragma unroll
      for (int mi = 0; mi < 4; ++mi)
        acc[mi][ni] = __builtin_amdgcn_mfma_f32_16x16x32_bf16(af[mi], bb, acc[mi][ni], 0, 0, 0);
    }
    __syncthreads();
  }

  int rowq = (lane >> 4) * 4;
#pragma unroll
  for (int mi = 0; mi < 4; ++mi) {
#pragma unroll
    for (int j = 0; j < 4; ++j) {
      int rg = tile_row + wm + mi * 16 + rowq + j;
      if (rg < row_end) {
        int tok = row_token[rg];
        float w = row_wt[rg];
#pragma unroll
        for (int ni = 0; ni < 4; ++ni) {
          atomicAdd(&out[(size_t)tok * DIM + n0 + wn + ni * 16 + lr],
                    acc[mi][ni][j] * w);
        }
      }
    }
  }
}

// ================= FALLBACK PATH (round-1 kernels) ============================

#define PAD 8
__global__ __launch_bounds__(256) void k_gateup_fb(
    const __bf16* __restrict__ xbf, const float* __restrict__ gw,
    const float* __restrict__ uw, const int* __restrict__ row_token,
    const int* __restrict__ offsets, __bf16* __restrict__ abuf) {
  int e = blockIdx.z;
  int row_start = offsets[e], row_end = offsets[e + 1];
  int tile_row = row_start + blockIdx.y * 128;
  if (tile_row >= row_end) return;
  int n0 = blockIdx.x * 128;

  __shared__ __align__(16) __bf16 As[128][BK + PAD];
  __shared__ __align__(16) __bf16 Bgs[128][BK + PAD];
  __shared__ __align__(16) __bf16 Bus[128][BK + PAD];
  __shared__ int toks[128];

  int tid = threadIdx.x;
  if (tid < 128) {
    int r = tile_row + tid;
    toks[tid] = (r < row_end) ? row_token[r] : row_token[row_start];
  }
  __syncthreads();

  f32x4 accg[4][4]; f32x4 accu[4][4];
#pragma unroll
  for (int i = 0; i < 4; ++i)
#pragma unroll
    for (int j = 0; j < 4; ++j) { accg[i][j] = (f32x4)0.f; accu[i][j] = (f32x4)0.f; }

  int wid = tid >> 6, lane = tid & 63;
  int wm = (wid >> 1) * 64, wn = (wid & 1) * 64;
  int lr = lane & 15, lk = (lane >> 4) * 8;

  const float* gbase = gw + (size_t)e * DIM * FE + n0;
  const float* ubase = uw + (size_t)e * DIM * FE + n0;
  int n4 = (tid & 31) * 4;
  int kb = tid >> 5;

  for (int k0 = 0; k0 < DIM; k0 += BK) {
#pragma unroll
    for (int p = 0; p < 2; ++p) {
      int g = tid + p * 256;
      int r = g >> 2, kk = (g & 3) * 8;
      *(bf16x8*)&As[r][kk] = *(const bf16x8*)(xbf + (size_t)toks[r] * DIM + k0 + kk);
    }
#pragma unroll
    for (int p = 0; p < 4; ++p) {
      int k = kb + p * 8;
      const float4 vg = *(const float4*)(gbase + (size_t)(k0 + k) * FE + n4);
      const float4 vu = *(const float4*)(ubase + (size_t)(k0 + k) * FE + n4);
      Bgs[n4 + 0][k] = (__bf16)vg.x; Bgs[n4 + 1][k] = (__bf16)vg.y;
      Bgs[n4 + 2][k] = (__bf16)vg.z; Bgs[n4 + 3][k] = (__bf16)vg.w;
      Bus[n4 + 0][k] = (__bf16)vu.x; Bus[n4 + 1][k] = (__bf16)vu.y;
      Bus[n4 + 2][k] = (__bf16)vu.z; Bus[n4 + 3][k] = (__bf16)vu.w;
    }
    __syncthreads();

    bf16x8 af[4];
#pragma unroll
    for (int mi = 0; mi < 4; ++mi)
      af[mi] = *(const bf16x8*)&As[wm + mi * 16 + lr][lk];
#pragma unroll
    for (int ni = 0; ni < 4; ++ni) {
      bf16x8 bg = *(const bf16x8*)&Bgs[wn + ni * 16 + lr][lk];
      bf16x8 bu = *(const bf16x8*)&Bus[wn + ni * 16 + lr][lk];
#pragma unroll
      for (int mi = 0; mi < 4; ++mi) {
        accg[mi][ni] = __builtin_amdgcn_mfma_f32_16x16x32_bf16(af[mi], bg, accg[mi][ni], 0, 0, 0);
        accu[mi][ni] = __builtin_amdgcn_mfma_f32_16x16x32_bf16(af[mi], bu, accu[mi][ni], 0, 0, 0);
      }
    }
    __syncthreads();
  }

  int rowq = (lane >> 4) * 4;
#pragma unroll
  for (int mi = 0; mi < 4; ++mi) {
#pragma unroll
    for (int ni = 0; ni < 4; ++ni) {
#pragma unroll
      for (int j = 0; j < 4; ++j) {
        int rg = tile_row + wm + mi * 16 + rowq + j;
        if (rg < row_end) {
          float g = accg[mi][ni][j], u = accu[mi][ni][j];
          float sig = 1.f / (1.f + __expf(-g));
          abuf[(size_t)rg * FE + n0 + wn + ni * 16 + lr] = (__bf16)(g * sig * u);
        }
      }
    }
  }
}

__global__ __launch_bounds__(256) void k_down_fb(
    const __bf16* __restrict__ abuf, const float* __restrict__ dw,
    const int* __restrict__ row_token, const float* __restrict__ row_wt,
    const int* __restrict__ offsets, float* __restrict__ out) {
  int e = blockIdx.z;
  int row_start = offsets[e], row_end = offsets[e + 1];
  int tile_row = row_start + blockIdx.y * 128;
  if (tile_row >= row_end) return;
  int n0 = blockIdx.x * 128;

  __shared__ __align__(16) __bf16 As[128][BK + PAD];
  __shared__ __align__(16) __bf16 Bs[128][BK + PAD];

  int tid = threadIdx.x;
  f32x4 acc[4][4];
#pragma unroll
  for (int i = 0; i < 4; ++i)
#pragma unroll
    for (int j = 0; j < 4; ++j) acc[i][j] = (f32x4)0.f;

  int wid = tid >> 6, lane = tid & 63;
  int wm = (wid >> 1) * 64, wn = (wid & 1) * 64;
  int lr = lane & 15, lk = (lane >> 4) * 8;

  const float* dbase = dw + (size_t)e * FE * DIM + n0;
  int n4 = (tid & 31) * 4;
  int kb = tid >> 5;

  for (int k0 = 0; k0 < FE; k0 += BK) {
#pragma unroll
    for (int p = 0; p < 2; ++p) {
      int g = tid + p * 256;
      int r = g >> 2, kk = (g & 3) * 8;
      *(bf16x8*)&As[r][kk] = *(const bf16x8*)(abuf + (size_t)(tile_row + r) * FE + k0 + kk);
    }
#pragma unroll
    for (int p = 0; p < 4; ++p) {
      int k = kb + p * 8;
      const float4 vb = *(const float4*)(dbase + (size_t)(k0 + k) * DIM + n4);
      Bs[n4 + 0][k] = (__bf16)vb.x; Bs[n4 + 1][k] = (__bf16)vb.y;
      Bs[n4 + 2][k] = (__bf16)vb.z; Bs[n4 + 3][k] = (__bf16)vb.w;
    }
    __syncthreads();

    bf16x8 af[4];
#pragma unroll
    for (int mi = 0; mi < 4; ++mi)
      af[mi] = *(const bf16x8*)&As[wm + mi * 16 + lr][lk];
#pragma unroll
    for (int ni = 0; ni < 4; ++ni) {
      bf16x8 bb = *(const bf16x8*)&Bs[wn + ni * 16 + lr][lk];
#pragma unroll
      for (int mi = 0; mi < 4; ++mi)
        acc[mi][ni] = __builtin_amdgcn_mfma_f32_16x16x32_bf16(af[mi], bb, acc[mi][ni], 0, 0, 0);
    }
    __syncthreads();
  }

  int rowq = (lane >> 4) * 4;
#pragma unroll
  for (int mi = 0; mi < 4; ++mi) {
#pragma unroll
    for (int j = 0; j < 4; ++j) {
      int rg = tile_row + wm + mi * 16 + rowq + j;
      if (rg < row_end) {
        int tok = row_token[rg];
        float w = row_wt[rg];
#pragma unroll
        for (int ni = 0; ni < 4; ++ni) {
          atomicAdd(&out[(size_t)tok * DIM + n0 + wn + ni * 16 + lr],
                    acc[mi][ni][j] * w);
        }
      }
    }
  }
}

extern "C" void kernel_launch(void* const* d_in, const int* in_sizes, int n_in,
                              void* d_out, int out_size, void* d_ws, size_t ws_size,
                              hipStream_t stream) {
  const float* x  = (const float*)d_in[0];
  const float* rw = (const float*)d_in[1];
  const float* nw = (const float*)d_in[2];
  const float* gw = (const float*)d_in[3];
  const float* uw = (const float*)d_in[4];
  const float* dwp= (const float*)d_in[5];
  float* out = (float*)d_out;

  char* p = (char*)d_ws;
  int* counts    = (int*)p;
  int* cursor    = (int*)(p + 32);
  int* offsets   = (int*)(p + 64);
  int* topi      = (int*)(p + 256);
  float* topw    = (float*)(p + 256 + 32768);
  int* row_token = (int*)(p + 256 + 65536);
  float* row_wt  = (float*)(p + 256 + 98304);
  __bf16* xbf    = (__bf16*)(p + 256 + 131072);
  __bf16* abuf   = xbf + (size_t)TOK * DIM;
  __bf16* gwt    = abuf + ((size_t)2 * TOK + 128) * FE;
  __bf16* uwt    = gwt + (size_t)NE * DIM * FE;
  __bf16* dwt    = uwt + (size_t)NE * DIM * FE;

  size_t need = 256 + 131072 +
                ((size_t)TOK * DIM + ((size_t)2 * TOK + 128) * FE) * 2 +
                3 * (size_t)NE * DIM * FE * 2;
  bool fast = ws_size >= need;

  hipMemsetAsync(p, 0, 64, stream);
  hipMemsetAsync(d_out, 0, (size_t)TOK * DIM * sizeof(float), stream);

  if (fast) {
    // gate/up: [E][D][FE] -> [E][FE][D];  down: [E][FE][D] -> [E][D][FE]
    k_tcvt2<<<dim3(FE / 32, DIM / 64, NE), 256, 0, stream>>>(gw, gwt, DIM, FE);
    k_tcvt2<<<dim3(FE / 32, DIM / 64, NE), 256, 0, stream>>>(uw, uwt, DIM, FE);
    k_tcvt2<<<dim3(DIM / 32, FE / 64, NE), 256, 0, stream>>>(dwp, dwt, FE, DIM);
  }

  k_router<<<TOK, 256, 0, stream>>>(x, rw, nw, xbf, topi, topw, counts);
  k_prefix<<<1, 64, 0, stream>>>(counts, offsets, cursor);
  k_place<<<(TOK + 255) / 256, 256, 0, stream>>>(topi, topw, cursor, row_token, row_wt);

  if (fast) {
    k_gateup3<<<dim3(FE / 64, 32, NE), 256, 0, stream>>>(xbf, gwt, uwt, row_token, offsets, abuf);
    k_down3<<<dim3(DIM / 128, 32, NE), 256, 0, stream>>>(abuf, dwt, row_token, row_wt, offsets, out);
  } else {
    k_gateup_fb<<<dim3(FE / 128, 32, NE), 256, 0, stream>>>(xbf, gw, uw, row_token, offsets, abuf);
    k_down_fb<<<dim3(DIM / 128, 32, NE), 256, 0, stream>>>(abuf, dwp, row_token, row_wt, offsets, out);
  }
}